// Round 1
// baseline (307.021 us; speedup 1.0000x reference)
//
#include <hip/hip_runtime.h>
#include <hip/hip_bf16.h>

#define HEADS 12
#define HD 64
#define WIN 65
#define PADW 32
#define EMBED 768
#define LSEQ 2048
#define QKV_N (3 * HEADS * HD)   // 2304

// Static scratch (avoids ws_size assumptions). Fully overwritten every call.
__device__ float g_qkv[LSEQ * QKV_N];          // 18.9 MB
__device__ float g_attn[LSEQ * HEADS * HD];    // 6.3 MB

// ---------------------------------------------------------------------------
// fp32 tiled GEMM: C[M,N] = A[M,K] @ B[K,N] (+ bias). M%64==0, N%64==0, K%16==0
// block = 256 threads (16x16), tile 64x64, BK=16, 4x4 per thread.
// ---------------------------------------------------------------------------
__global__ __launch_bounds__(256) void gemm_fp32(
    const float* __restrict__ A, const float* __restrict__ B,
    const float* __restrict__ bias, float* __restrict__ C,
    int M, int N, int K) {
  __shared__ float As[16][68];   // [k][m], padded stride 68: stores 2-way, reads broadcast
  __shared__ float Bs[16][64];   // [k][n]: stores stride-1, reads b128 2-way (free)

  const int tid = threadIdx.x;
  const int tx = tid & 15;        // n-quad
  const int ty = tid >> 4;        // m-quad
  const int m0 = blockIdx.y * 64;
  const int n0 = blockIdx.x * 64;

  float acc[4][4] = {};

  for (int k0 = 0; k0 < K; k0 += 16) {
    // A tile: 64 m x 16 k. thread: kk = tid%16, m = tid/16 + 16*p
    const int ka = tid & 15;
    const int ma = tid >> 4;
#pragma unroll
    for (int p = 0; p < 4; ++p) {
      int m = ma + p * 16;
      As[ka][m] = A[(size_t)(m0 + m) * K + k0 + ka];
    }
    // B tile: 16 k x 64 n. thread: n = tid%64, kk = tid/64 + 4*p
    const int nb = tid & 63;
    const int kb = tid >> 6;
#pragma unroll
    for (int p = 0; p < 4; ++p) {
      int kk = kb + p * 4;
      Bs[kk][nb] = B[(size_t)(k0 + kk) * N + n0 + nb];
    }
    __syncthreads();

#pragma unroll
    for (int kk = 0; kk < 16; ++kk) {
      float4 a4 = *(const float4*)&As[kk][ty * 4];
      float4 b4 = *(const float4*)&Bs[kk][tx * 4];
      float av[4] = {a4.x, a4.y, a4.z, a4.w};
      float bv[4] = {b4.x, b4.y, b4.z, b4.w};
#pragma unroll
      for (int i = 0; i < 4; ++i)
#pragma unroll
        for (int j = 0; j < 4; ++j)
          acc[i][j] += av[i] * bv[j];
    }
    __syncthreads();
  }

#pragma unroll
  for (int i = 0; i < 4; ++i) {
    int row = m0 + ty * 4 + i;
#pragma unroll
    for (int j = 0; j < 4; ++j) {
      int col = n0 + tx * 4 + j;
      float v = acc[i][j];
      if (bias) v += bias[col];
      C[(size_t)row * N + col] = v;
    }
  }
}

// ---------------------------------------------------------------------------
// Windowed attention. One block = 32 consecutive l for one head. 4 waves,
// each wave serializes over 8 l values; lane=w for scores, lane=d for PV.
// Zero-filled out-of-range K/V rows reproduce reference zero-pad semantics
// (score=0 participates in softmax; v=0 contributes nothing).
// ---------------------------------------------------------------------------
#define TL 32
#define SPAN (TL + 64)   // 96 rows: l0-32 .. l0+TL+31

__global__ __launch_bounds__(256) void attn_win(
    const float* __restrict__ qkv, float* __restrict__ out) {
  const int blk = blockIdx.x;
  const int h = blk % HEADS;
  const int l0 = (blk / HEADS) * TL;

  __shared__ float Ks[SPAN][HD + 1];
  __shared__ float Vs[SPAN][HD + 1];
  __shared__ float Qs[TL][HD];

  const int tid = threadIdx.x;
  const int dload = tid & 63;
  // load K/V window rows (4 rows per pass)
  for (int r = tid >> 6; r < SPAN; r += 4) {
    int l = l0 - PADW + r;
    float kv = 0.f, vv = 0.f;
    if (l >= 0 && l < LSEQ) {
      const float* base = qkv + (size_t)l * QKV_N + h * (3 * HD);
      kv = base[HD + dload];
      vv = base[2 * HD + dload];
    }
    Ks[r][dload] = kv;
    Vs[r][dload] = vv;
  }
  // load Q rows
  for (int r = tid >> 6; r < TL; r += 4) {
    int l = l0 + r;
    Qs[r][dload] = qkv[(size_t)l * QKV_N + h * (3 * HD) + dload];
  }
  __syncthreads();

  const int wave = tid >> 6;
  const int lane = tid & 63;

  for (int li = wave; li < TL; li += 4) {
    // scores: lane w = lane computes dot(Q[li], K[li+w]) for w in [0,64)
    float s = 0.f;
#pragma unroll
    for (int d = 0; d < HD; ++d)
      s += Qs[li][d] * Ks[li + lane][d];
    s *= 0.125f;

    // 65th window position (w=64): lane-parallel partial + reduce
    float p64 = Qs[li][lane] * Ks[li + 64][lane];
#pragma unroll
    for (int off = 32; off > 0; off >>= 1) p64 += __shfl_down(p64, off);
    float s64 = __shfl(p64, 0) * 0.125f;

    // softmax over 65 (64 lane-resident + s64)
    float m = s;
#pragma unroll
    for (int off = 32; off > 0; off >>= 1) m = fmaxf(m, __shfl_xor(m, off));
    m = fmaxf(m, s64);
    float p = __expf(s - m);
    float e64 = __expf(s64 - m);
    float denom = p;
#pragma unroll
    for (int off = 32; off > 0; off >>= 1) denom += __shfl_xor(denom, off);
    denom += e64;
    float inv = 1.f / denom;

    // PV: lane = d. weight_w broadcast via shuffle.
    float o = e64 * inv * Vs[li + 64][lane];
#pragma unroll
    for (int w = 0; w < 64; ++w) {
      float wt = __shfl(p, w) * inv;
      o += wt * Vs[li + w][lane];
    }
    out[(size_t)(l0 + li) * (HEADS * HD) + h * HD + lane] = o;
  }
}

extern "C" void kernel_launch(void* const* d_in, const int* in_sizes, int n_in,
                              void* d_out, int out_size, void* d_ws, size_t ws_size,
                              hipStream_t stream) {
  const float* x     = (const float*)d_in[0];   // [2048, 768]
  const float* w_qkv = (const float*)d_in[1];   // [768, 2304]
  const float* w_out = (const float*)d_in[2];   // [768, 768]
  const float* b_out = (const float*)d_in[3];   // [768]
  float* out = (float*)d_out;                   // [2048, 768]

  float* qkv;
  float* attn;
  hipGetSymbolAddress((void**)&qkv, HIP_SYMBOL(g_qkv));
  hipGetSymbolAddress((void**)&attn, HIP_SYMBOL(g_attn));

  // 1) qkv = x @ w_qkv          (2048x768 @ 768x2304)
  gemm_fp32<<<dim3(QKV_N / 64, LSEQ / 64), 256, 0, stream>>>(
      x, w_qkv, nullptr, qkv, LSEQ, QKV_N, EMBED);

  // 2) windowed attention -> attn [2048, 768]
  attn_win<<<(LSEQ / TL) * HEADS, 256, 0, stream>>>(qkv, attn);

  // 3) out = attn @ w_out + b_out  (2048x768 @ 768x768)
  gemm_fp32<<<dim3(EMBED / 64, LSEQ / 64), 256, 0, stream>>>(
      attn, w_out, b_out, out, LSEQ, EMBED, EMBED);
}

// Round 2
// 134.570 us; speedup vs baseline: 2.2815x; 2.2815x over previous
//
#include <hip/hip_runtime.h>
#include <hip/hip_bf16.h>

#define HEADS 12
#define HD 64
#define PADW 32
#define EMBED 768
#define LSEQ 2048
#define QKV_N (3 * HEADS * HD)   // 2304

typedef short short8 __attribute__((ext_vector_type(8)));
typedef short short4v __attribute__((ext_vector_type(4)));
typedef float f32x4 __attribute__((ext_vector_type(4)));

// Static scratch, fully overwritten every call (poison-safe).
__device__ short g_xb[LSEQ * EMBED];        // x bf16           [2048][768]
__device__ short g_wqkvT[QKV_N * EMBED];    // w_qkv^T bf16     [2304][768]
__device__ short g_woutT[EMBED * EMBED];    // w_out^T bf16     [768][768]
__device__ float g_qkv[LSEQ * QKV_N];       // qkv fp32         [2048][2304]
__device__ short g_attnb[LSEQ * EMBED];     // attn out bf16    [2048][768]

__device__ __forceinline__ short f2bf(float f) {
  unsigned x = __builtin_bit_cast(unsigned, f);
  x += 0x7fffu + ((x >> 16) & 1u);   // RNE
  return (short)(x >> 16);
}

#define GLB(p) ((const __attribute__((address_space(1))) void*)(p))
#define LDS(p) ((__attribute__((address_space(3))) void*)(p))

// ---------------------------------------------------------------------------
// prep kernels
// ---------------------------------------------------------------------------
__global__ __launch_bounds__(256) void cast_bf16(const float* __restrict__ in,
                                                 short* __restrict__ out) {
  int i = blockIdx.x * 256 + threadIdx.x;
  float4 v = ((const float4*)in)[i];
  short4v o;
  o[0] = f2bf(v.x); o[1] = f2bf(v.y); o[2] = f2bf(v.z); o[3] = f2bf(v.w);
  ((short4v*)out)[i] = o;
}

// W[K][N] fp32 -> WT[N][K] bf16
__global__ __launch_bounds__(256) void transpose_cast(
    const float* __restrict__ W, short* __restrict__ WT, int K, int N) {
  __shared__ float T[32][33];
  int tx = threadIdx.x & 31, ty = threadIdx.x >> 5;
  int n0 = blockIdx.x * 32, k0 = blockIdx.y * 32;
#pragma unroll
  for (int p = 0; p < 4; ++p)
    T[ty + p * 8][tx] = W[(size_t)(k0 + ty + p * 8) * N + n0 + tx];
  __syncthreads();
#pragma unroll
  for (int p = 0; p < 4; ++p)
    WT[(size_t)(n0 + ty + p * 8) * K + k0 + tx] = f2bf(T[tx][ty + p * 8]);
}

// ---------------------------------------------------------------------------
// bf16 MFMA GEMM: C[M,N] = A[M,K] @ Bt[N,K]^T (+bias). Tile BM x 64, BK=32.
// 256 threads = 4 waves in 2x2; wave tile (BM/2) x 32; 16x16x32 MFMA.
// ---------------------------------------------------------------------------
template <int BM>
__global__ __launch_bounds__(256) void gemm_bf16(
    const short* __restrict__ A, const short* __restrict__ Bt,
    const float* __restrict__ bias, float* __restrict__ C,
    int M, int N, int K) {
  constexpr int MT = BM / 32;            // m-frags per wave (4 or 2)
  constexpr int AC = BM / 64;            // A staging instrs per wave (2 or 1)
  __shared__ short Alds[BM * 32];
  __shared__ short Blds[64 * 32];

  const int tid = threadIdx.x;
  const int wv = tid >> 6, lane = tid & 63;
  const int wm = wv >> 1, wn = wv & 1;
  const int lanelo = lane & 15, quad = lane >> 4;
  const int m0 = blockIdx.y * BM, n0 = blockIdx.x * 64;
  const int srow = lane >> 2, schk = lane & 3;   // staging: 16 rows x 4 chunks

  f32x4 acc[MT][2] = {};

  for (int k0 = 0; k0 < K; k0 += 32) {
    // stage A: BM/16 chunks of 16 rows, AC per wave
#pragma unroll
    for (int c = 0; c < AC; ++c) {
      int chunk = wv * AC + c;
      const short* ga = A + (size_t)(m0 + chunk * 16 + srow) * K + k0 + schk * 8;
      __builtin_amdgcn_global_load_lds(GLB(ga), LDS(&Alds[chunk * 16 * 32]), 16, 0, 0);
    }
    // stage Bt: 4 chunks, 1 per wave
    {
      const short* gb = Bt + (size_t)(n0 + wv * 16 + srow) * K + k0 + schk * 8;
      __builtin_amdgcn_global_load_lds(GLB(gb), LDS(&Blds[wv * 16 * 32]), 16, 0, 0);
    }
    __syncthreads();

    short8 af[MT], bfr[2];
#pragma unroll
    for (int mt = 0; mt < MT; ++mt)
      af[mt] = *(const short8*)&Alds[(wm * (MT * 16) + mt * 16 + lanelo) * 32 + quad * 8];
#pragma unroll
    for (int nt = 0; nt < 2; ++nt)
      bfr[nt] = *(const short8*)&Blds[(wn * 32 + nt * 16 + lanelo) * 32 + quad * 8];
#pragma unroll
    for (int mt = 0; mt < MT; ++mt)
#pragma unroll
      for (int nt = 0; nt < 2; ++nt)
        acc[mt][nt] = __builtin_amdgcn_mfma_f32_16x16x32_bf16(af[mt], bfr[nt], acc[mt][nt], 0, 0, 0);
    __syncthreads();
  }

  float bv[2];
#pragma unroll
  for (int nt = 0; nt < 2; ++nt) {
    int col = n0 + wn * 32 + nt * 16 + lanelo;
    bv[nt] = bias ? bias[col] : 0.f;
  }
#pragma unroll
  for (int mt = 0; mt < MT; ++mt)
#pragma unroll
    for (int nt = 0; nt < 2; ++nt) {
      int col = n0 + wn * 32 + nt * 16 + lanelo;
#pragma unroll
      for (int r = 0; r < 4; ++r) {
        int row = m0 + wm * (MT * 16) + mt * 16 + quad * 4 + r;
        C[(size_t)row * N + col] = acc[mt][nt][r] + bv[nt];
      }
    }
}

// ---------------------------------------------------------------------------
// MFMA windowed attention. Block = 64 rows x 1 head. 4 waves; wave wv owns the
// 16-row strip [wv*16, wv*16+16). Span = 128 K/V rows starting at l0-32.
// S (16x128) = Q.K^T via MFMA (frags straight from global fp32, cvt to bf16),
// masked softmax, P through LDS (C-layout -> A-layout), O = P.V via MFMA.
// ---------------------------------------------------------------------------
__global__ __launch_bounds__(256) void attn_mfma(
    const float* __restrict__ qkv, short* __restrict__ attnb) {
  const int blk = blockIdx.x;
  const int h = blk % HEADS;
  const int l0 = (blk / HEADS) * 64;
  const int sb = l0 - PADW;                 // span base (may be <0)
  const bool interior = (sb >= 0) && (sb + 127 < LSEQ);

  const int tid = threadIdx.x;
  const int wv = tid >> 6, lane = tid & 63;
  const int lanelo = lane & 15, quad = lane >> 4;
  const int qoff = h * 192, koff = h * 192 + 64, voff = h * 192 + 128;

  __shared__ short P_lds[64 * 136];        // rows padded to 136 bf16

  // ---- Q a-frags (always in-bounds): rows l0 + wv*16 + lanelo
  short8 aq[2];
  {
    const float* qp = qkv + (size_t)(l0 + wv * 16 + lanelo) * QKV_N + qoff;
#pragma unroll
    for (int ks = 0; ks < 2; ++ks) {
      const float4* p = (const float4*)(qp + ks * 32 + quad * 8);
      float4 f0 = p[0], f1 = p[1];
      short8 a;
      a[0]=f2bf(f0.x); a[1]=f2bf(f0.y); a[2]=f2bf(f0.z); a[3]=f2bf(f0.w);
      a[4]=f2bf(f1.x); a[5]=f2bf(f1.y); a[6]=f2bf(f1.z); a[7]=f2bf(f1.w);
      aq[ks] = a;
    }
  }

  // ---- S = Q.K^T : 8 n-tiles x 2 k-steps
  f32x4 sacc[8] = {};
#pragma unroll
  for (int nt = 0; nt < 8; ++nt) {
    int gl = sb + nt * 16 + lanelo;        // K row for this lane
    bool ok = interior || ((unsigned)gl < (unsigned)LSEQ);
    const float* kp = qkv + (size_t)gl * QKV_N + koff;
#pragma unroll
    for (int ks = 0; ks < 2; ++ks) {
      short8 bk;
      if (ok) {
        const float4* p = (const float4*)(kp + ks * 32 + quad * 8);
        float4 f0 = p[0], f1 = p[1];
        bk[0]=f2bf(f0.x); bk[1]=f2bf(f0.y); bk[2]=f2bf(f0.z); bk[3]=f2bf(f0.w);
        bk[4]=f2bf(f1.x); bk[5]=f2bf(f1.y); bk[6]=f2bf(f1.z); bk[7]=f2bf(f1.w);
      } else {
#pragma unroll
        for (int j = 0; j < 8; ++j) bk[j] = 0;
      }
      sacc[nt] = __builtin_amdgcn_mfma_f32_16x16x32_bf16(aq[ks], bk, sacc[nt], 0, 0, 0);
    }
  }

  // ---- masked softmax per row (rows = quad*4+r within strip)
  float rmax[4] = {-1e30f, -1e30f, -1e30f, -1e30f};
#pragma unroll
  for (int nt = 0; nt < 8; ++nt)
#pragma unroll
    for (int r = 0; r < 4; ++r) {
      int li = wv * 16 + quad * 4 + r;     // block-local query row
      int col = nt * 16 + lanelo;          // span offset
      int widx = col - li;
      float s = (widx >= 0 && widx <= 64) ? sacc[nt][r] * 0.125f : -1e30f;
      sacc[nt][r] = s;
      rmax[r] = fmaxf(rmax[r], s);
    }
#pragma unroll
  for (int r = 0; r < 4; ++r) {
#pragma unroll
    for (int off = 1; off < 16; off <<= 1)
      rmax[r] = fmaxf(rmax[r], __shfl_xor(rmax[r], off));
  }
  float rsum[4] = {0.f, 0.f, 0.f, 0.f};
#pragma unroll
  for (int nt = 0; nt < 8; ++nt)
#pragma unroll
    for (int r = 0; r < 4; ++r) {
      float p = __expf(sacc[nt][r] - rmax[r]);
      sacc[nt][r] = p;
      rsum[r] += p;
    }
#pragma unroll
  for (int r = 0; r < 4; ++r) {
#pragma unroll
    for (int off = 1; off < 16; off <<= 1)
      rsum[r] += __shfl_xor(rsum[r], off);
    rsum[r] = 1.f / rsum[r];
  }
  // write normalized P to LDS in A-layout: P_lds[row][col]
#pragma unroll
  for (int nt = 0; nt < 8; ++nt)
#pragma unroll
    for (int r = 0; r < 4; ++r) {
      int row = wv * 16 + quad * 4 + r;
      int col = nt * 16 + lanelo;
      P_lds[row * 136 + col] = f2bf(sacc[nt][r] * rsum[r]);
    }
  __syncthreads();

  // ---- O = P.V : 4 d-tiles x 4 k-steps of 32
  f32x4 oacc[4] = {};
#pragma unroll
  for (int ks = 0; ks < 4; ++ks) {
    short8 ap = *(const short8*)&P_lds[(wv * 16 + lanelo) * 136 + ks * 32 + quad * 8];
    int r0 = ks * 32 + quad * 8;           // first V row of this lane's 8
    bool allin = interior || ((sb + r0 >= 0) && (sb + r0 + 7 < LSEQ));
#pragma unroll
    for (int nt = 0; nt < 4; ++nt) {
      const float* vp = qkv + (size_t)(sb + r0) * QKV_N + voff + nt * 16 + lanelo;
      short8 bv;
      if (allin) {
        float t[8];
#pragma unroll
        for (int j = 0; j < 8; ++j) t[j] = vp[(size_t)j * QKV_N];
#pragma unroll
        for (int j = 0; j < 8; ++j) bv[j] = f2bf(t[j]);
      } else {
#pragma unroll
        for (int j = 0; j < 8; ++j) {
          int gl = sb + r0 + j;
          bv[j] = ((unsigned)gl < (unsigned)LSEQ) ? f2bf(vp[(size_t)j * QKV_N]) : (short)0;
        }
      }
      oacc[nt] = __builtin_amdgcn_mfma_f32_16x16x32_bf16(ap, bv, oacc[nt], 0, 0, 0);
    }
  }

  // ---- store O as bf16 [2048][768]
#pragma unroll
  for (int nt = 0; nt < 4; ++nt)
#pragma unroll
    for (int r = 0; r < 4; ++r) {
      int row = l0 + wv * 16 + quad * 4 + r;
      int col = h * 64 + nt * 16 + lanelo;
      attnb[(size_t)row * EMBED + col] = f2bf(oacc[nt][r]);
    }
}

extern "C" void kernel_launch(void* const* d_in, const int* in_sizes, int n_in,
                              void* d_out, int out_size, void* d_ws, size_t ws_size,
                              hipStream_t stream) {
  const float* x     = (const float*)d_in[0];   // [2048, 768]
  const float* w_qkv = (const float*)d_in[1];   // [768, 2304]
  const float* w_out = (const float*)d_in[2];   // [768, 768]
  const float* b_out = (const float*)d_in[3];   // [768]
  float* out = (float*)d_out;                   // [2048, 768]

  short *xb, *wqkvT, *woutT, *attnb;
  float* qkv;
  hipGetSymbolAddress((void**)&xb,    HIP_SYMBOL(g_xb));
  hipGetSymbolAddress((void**)&wqkvT, HIP_SYMBOL(g_wqkvT));
  hipGetSymbolAddress((void**)&woutT, HIP_SYMBOL(g_woutT));
  hipGetSymbolAddress((void**)&qkv,   HIP_SYMBOL(g_qkv));
  hipGetSymbolAddress((void**)&attnb, HIP_SYMBOL(g_attnb));

  // prep: casts + weight transposes
  cast_bf16<<<(LSEQ * EMBED) / (256 * 4), 256, 0, stream>>>(x, xb);
  transpose_cast<<<dim3(QKV_N / 32, EMBED / 32), 256, 0, stream>>>(w_qkv, wqkvT, EMBED, QKV_N);
  transpose_cast<<<dim3(EMBED / 32, EMBED / 32), 256, 0, stream>>>(w_out, woutT, EMBED, EMBED);

  // qkv = x @ w_qkv   (fp32 out)
  gemm_bf16<128><<<dim3(QKV_N / 64, LSEQ / 128), 256, 0, stream>>>(
      xb, wqkvT, nullptr, qkv, LSEQ, QKV_N, EMBED);

  // windowed attention -> attnb (bf16)
  attn_mfma<<<(LSEQ / 64) * HEADS, 256, 0, stream>>>(qkv, attnb);

  // out = attn @ w_out + b_out
  gemm_bf16<64><<<dim3(EMBED / 64, LSEQ / 64), 256, 0, stream>>>(
      attnb, woutT, b_out, out, LSEQ, EMBED, EMBED);
}